// Round 14
// baseline (247.026 us; speedup 1.0000x reference)
//
#include <hip/hip_runtime.h>
#include <stdint.h>

typedef __bf16 bf16x8 __attribute__((ext_vector_type(8)));
typedef float f32x4 __attribute__((ext_vector_type(4)));
typedef unsigned short u16x8 __attribute__((ext_vector_type(8)));

typedef const __attribute__((address_space(1))) void* gas_ptr;
typedef __attribute__((address_space(3))) void* las_ptr;
typedef const __attribute__((address_space(3))) char* lds_c3;

__device__ __forceinline__ void gload16(const void* g, void* l) {
  __builtin_amdgcn_global_load_lds((gas_ptr)g, (las_ptr)l, 16, 0, 0);
}

__device__ __forceinline__ bf16x8 dsread16(const char* p) {
  bf16x8 r;
  asm volatile("ds_read_b128 %0, %1" : "=v"(r) : "v"((lds_c3)p));
  return r;
}
__device__ __forceinline__ void dswrite2(char* p, uint32_t v) {
  asm volatile("ds_write_b16 %0, %1" : : "v"((las_ptr)p), "v"(v));
}
template <int OFF>
__device__ __forceinline__ float dswz(float x) {
  float r;
  asm volatile("ds_swizzle_b32 %0, %1 offset:%c2" : "=v"(r) : "v"(x), "i"(OFF));
  return r;
}

__device__ __forceinline__ unsigned short f2bf(float f) {
  uint32_t u = __float_as_uint(f);
  u += 0x7FFFu + ((u >> 16) & 1u);
  return (unsigned short)(u >> 16);
}
__device__ __forceinline__ float bf2f(unsigned short u) {
  return __uint_as_float(((uint32_t)u) << 16);
}

#define SB __builtin_amdgcn_sched_barrier(0)
#define BAR __builtin_amdgcn_s_barrier()
#define LGK0 asm volatile("s_waitcnt lgkmcnt(0)")

// ---------------- fused prep: all f32->bf16 converts + RoPE table ----------
__device__ __forceinline__ void conv8(const float* __restrict__ src,
                                      unsigned short* __restrict__ dst, int i) {
  const float4* s4 = (const float4*)src;
  float4 a = s4[2 * i], b = s4[2 * i + 1];
  u16x8 r;
  r[0] = f2bf(a.x); r[1] = f2bf(a.y); r[2] = f2bf(a.z); r[3] = f2bf(a.w);
  r[4] = f2bf(b.x); r[5] = f2bf(b.y); r[6] = f2bf(b.z); r[7] = f2bf(b.w);
  *(u16x8*)&dst[(size_t)i * 8] = r;
}

__global__ __launch_bounds__(256)
void prep_all(const float* __restrict__ x, const float* __restrict__ h_a,
              const float* __restrict__ h_t,
              const float* W0, const float* W1, const float* W2, const float* W3,
              const float* W4, const float* W5, const float* W6, const float* W7,
              const int* __restrict__ eptr,
              unsigned short* __restrict__ XB, unsigned short* __restrict__ HAB,
              unsigned short* __restrict__ HTB, unsigned short* __restrict__ WW,
              float* __restrict__ cosb, float* __restrict__ sinb) {
  const int blk = blockIdx.x, tid = threadIdx.x;
  if (blk < 4096) {
    conv8(x, XB, blk * 256 + tid);
  } else if (blk < 6144) {
    conv8(h_a, HAB, (blk - 4096) * 256 + tid);
  } else if (blk < 8192) {
    conv8(h_t, HTB, (blk - 6144) * 256 + tid);
  } else if (blk < 12288) {
    const int w = (blk - 8192) >> 9;
    const int i = ((blk - 8192) & 511) * 256 + tid;
    const float* wp;
    switch (w) {
      case 0: wp = W0; break; case 1: wp = W1; break;
      case 2: wp = W2; break; case 3: wp = W3; break;
      case 4: wp = W4; break; case 5: wp = W5; break;
      case 6: wp = W6; break; default: wp = W7; break;
    }
    conv8(wp + (size_t)(*eptr) * 1048576, WW + (size_t)w * 1048576, i);
  } else {
    const int i = (blk - 12288) * 256 + tid;  // 0..65535
    const int t = i >> 7, d = i & 127;
    const int f = d & 63;
    float invf = expf(-0.14391156831212787f * (float)f);  // 10000^(-f/64)
    float ang = (float)t * invf;
    float s, c;
    sincosf(ang, &s, &c);
    cosb[i] = c;
    sinb[i] = s;
  }
}

// ======== 3-ring counted-vmcnt GEMM: BM=256, BN=128, BK=64, 8 waves =========
// r13-verified inner loop.
// MODE 0: fused Q+KV proj, grid 1024: swz<512 -> Q (RoPE LSEQ=512);
//         else KV (z streams, K RoPE LSEQ=256 / V transposed).
// MODE 2: O proj +resid -> bf16 X2 ; MODE 3: FFN +relu -> f32 (grid 256)
template <int MODE>
__global__ __launch_bounds__(512, 1)
void gemm3r(const unsigned short* __restrict__ A0, const unsigned short* __restrict__ A1,
            const unsigned short* __restrict__ A2,
            const unsigned short* __restrict__ W0, const unsigned short* __restrict__ W1,
            const unsigned short* __restrict__ W2, const unsigned short* __restrict__ W3,
            const unsigned short* __restrict__ W4, const unsigned short* __restrict__ W5,
            const float* __restrict__ bias0, const float* __restrict__ bias1,
            const float* __restrict__ bias2, const float* __restrict__ bias3,
            const float* __restrict__ bias4, const float* __restrict__ bias5,
            const int* __restrict__ eptr, const float* __restrict__ ctab,
            const float* __restrict__ stab,
            unsigned short* __restrict__ oQA, unsigned short* __restrict__ oQT,
            unsigned short* __restrict__ oKA, unsigned short* __restrict__ oKT,
            unsigned short* __restrict__ outV,
            const float* __restrict__ resid, unsigned short* __restrict__ outbf,
            float* __restrict__ outf) {
  __shared__ __align__(16) char AL[98304];
  __shared__ __align__(16) char BL[49152];
  const int tid = threadIdx.x;
  const int lane = tid & 63, wid = tid >> 6, fr = lane & 15, g = lane >> 4;
  const int wm = wid >> 1, wn = wid & 1;  // 4M x 2N
  const int id = blockIdx.x;
  const int e = *eptr;

  const unsigned short* Asel;
  const unsigned short* Wsel;
  const float* bias;
  int bm, bn, z = 0, half = 0, cb0;
  bool isQ = true;
  if constexpr (MODE == 0) {
    const int swz = (id & 7) * 128 + (id >> 3);  // bijective, grid 1024
    if (swz < 512) {
      bm = swz >> 4; bn = swz & 15;
    } else {
      isQ = false;
      const int s2 = swz - 512;
      z = s2 >> 8;
      bm = (s2 & 255) >> 4; bn = s2 & 15;
    }
    half = bn >> 3;
    cb0 = (bn & 7) * 128;
    Asel = isQ ? A0 : (z ? A2 : A1);
    Wsel = isQ ? (half ? W1 : W0) : (z ? (half ? W5 : W4) : (half ? W3 : W2));
    bias = (isQ ? (half ? bias1 : bias0)
                : (z ? (half ? bias5 : bias4) : (half ? bias3 : bias2))) + e * 1024;
  } else {
    const int swz = (id & 7) * 32 + (id >> 3);
    bm = swz >> 3; bn = swz & 7;
    cb0 = bn * 128;
    Asel = A0;
    Wsel = W0;
    bias = bias0 + e * 1024;
  }

  const char* Ab = (const char*)Asel + (size_t)bm * 256 * 2048;
  const char* Bb = (const char*)Wsel + (size_t)cb0 * 2048;

  const int csw = (((tid & 7) ^ ((tid >> 3) & 7)) << 4);
  const char* Ags = Ab + (tid >> 3) * 2048 + csw;
  const char* Bgs = Bb + (tid >> 3) * 2048 + csw;
  char* Ald = AL + tid * 16;
  char* Bld = BL + tid * 16;

#define STA(T, BUF)                                                         \
  { const char* s_ = Ags + (T) * 128;                                       \
    char* d_ = Ald + (BUF) * 32768;                                         \
    gload16(s_, d_);                  gload16(s_ + 131072, d_ + 8192);      \
    gload16(s_ + 262144, d_ + 16384); gload16(s_ + 393216, d_ + 24576); }
#define STB(T, BUF)                                                         \
  { const char* s_ = Bgs + (T) * 128;                                       \
    char* d_ = Bld + (BUF) * 16384;                                         \
    gload16(s_, d_);                  gload16(s_ + 131072, d_ + 8192); }

  const int lsw7 = fr & 7;
  const int ksel = (wid & 4) ? 4 : 0;
  const int cA = ((ksel + g) ^ lsw7) << 4;
  const int cB = (((4 - ksel) + g) ^ lsw7) << 4;
  const int arow = (wm * 64 + fr) * 128;
  const int brow = (wn * 64 + fr) * 128;

  f32x4 acc[4][4];
#pragma unroll
  for (int m = 0; m < 4; ++m)
#pragma unroll
    for (int n = 0; n < 4; ++n) acc[m][n] = f32x4{0.f, 0.f, 0.f, 0.f};
  bf16x8 af[4], bf[4];

#define RDAB(BASEA, BASEB, C)                                               \
  { const char* pa_ = (BASEA) + arow + (C);                                 \
    const char* pb_ = (BASEB) + brow + (C);                                 \
    _Pragma("unroll") for (int m = 0; m < 4; ++m)                           \
        af[m] = dsread16(pa_ + m * 2048);                                   \
    _Pragma("unroll") for (int n = 0; n < 4; ++n)                           \
        bf[n] = dsread16(pb_ + n * 2048); }

#define MF16                                                                \
  __builtin_amdgcn_s_setprio(1);                                            \
  _Pragma("unroll") for (int m = 0; m < 4; ++m)                             \
    _Pragma("unroll") for (int n = 0; n < 4; ++n)                           \
        acc[m][n] = __builtin_amdgcn_mfma_f32_16x16x32_bf16(                \
            af[m], bf[n], acc[m][n], 0, 0, 0);                              \
  __builtin_amdgcn_s_setprio(0);

  STA(0, 0); STB(0, 0); STA(1, 1); STB(1, 1);

  int bc = 0;
#pragma unroll 1
  for (int t = 0; t < 16; ++t) {
    SB;
    if (t <= 14) asm volatile("s_waitcnt vmcnt(6)");
    else         asm volatile("s_waitcnt vmcnt(0)");
    BAR; SB;
    const char* ALc = AL + bc * 32768;
    const char* BLc = BL + bc * 16384;
    const int bs = bc ? bc - 1 : 2;  // (t+2)%3
    RDAB(ALc, BLc, cA); SB;
    if (t <= 13) STA(t + 2, bs);
    SB; LGK0; SB;
    MF16 SB;
    RDAB(ALc, BLc, cB); SB;
    if (t <= 13) STB(t + 2, bs);
    SB; LGK0; SB;
    MF16 SB;
    bc = (bc == 2) ? 0 : bc + 1;
  }
#undef RDAB
#undef MF16
#undef STA
#undef STB

  // ---------------- epilogue ----------------
  const int wrow0 = bm * 256 + wm * 64;
#pragma unroll
  for (int m = 0; m < 4; ++m) {
#pragma unroll
    for (int n = 0; n < 4; ++n) {
      const int lc = wn * 64 + n * 16 + fr;
      const int gc = cb0 + lc;
      const float bv = bias[gc];
#pragma unroll
      for (int j = 0; j < 4; ++j) {
        const int grow = wrow0 + m * 16 + g * 4 + j;
        float v = acc[m][n][j] + bv;
        if constexpr (MODE == 0) {
          const int hh = gc >> 7, dd = gc & 127;
          if (isQ) {
            const int tt = grow & 511, bb = grow >> 9;
            float pv = __shfl_xor(v, 1);
            float cs = ctab[tt * 128 + dd], sn = stab[tt * 128 + dd];
            float rh = (dd & 1) ? pv : -pv;
            float o = v * cs + rh * sn;
            unsigned short* dst = half ? oQT : oQA;
            dst[(((size_t)(bb * 8 + hh) * 512 + tt) << 7) + dd] = f2bf(o);
          } else {
            const int tt = grow & 255, bb = grow >> 8;
            if (half == 0) {  // K: RoPE, LSEQ=256
              float pv = __shfl_xor(v, 1);
              float cs = ctab[tt * 128 + dd], sn = stab[tt * 128 + dd];
              float rh = (dd & 1) ? pv : -pv;
              float o = v * cs + rh * sn;
              unsigned short* dst = z ? oKT : oKA;
              dst[(((size_t)(bb * 8 + hh) * 256 + tt) << 7) + dd] = f2bf(o);
            } else {  // V: transposed (b,h,d,512)
              outV[(((size_t)(bb * 8 + hh) << 7) + dd) * 512 + z * 256 + tt] = f2bf(v);
            }
          }
        } else if constexpr (MODE == 2) {
          const size_t idx = ((size_t)grow << 10) + gc;
          outbf[idx] = f2bf(v + resid[idx]);  // X2 in bf16 (traffic halved)
        } else {
          const size_t idx = ((size_t)grow << 10) + gc;
          outf[idx] = fmaxf(v, 0.f);
        }
      }
    }
  }
}

// ---------------- fused dual-stream flash attention (r13: dbuf + XCD swz) --
__global__ __launch_bounds__(256, 2)
void attn_kernel(const unsigned short* __restrict__ QA, const unsigned short* __restrict__ QT,
                 const unsigned short* __restrict__ KA, const unsigned short* __restrict__ KT,
                 const unsigned short* __restrict__ VT,  // (b,h,d=128,n=512)
                 unsigned short* __restrict__ AO,        // (b,t,1024)
                 const float* __restrict__ gating, const int* __restrict__ eptr) {
  __shared__ unsigned short Ks[2][8192];
  __shared__ unsigned short Vs[2][8192];
  __shared__ unsigned short Ps[8192];
  const int tid = threadIdx.x, lane = tid & 63, wv = tid >> 6;
  const int fr = lane & 15, g = lane >> 4;
  const int id = blockIdx.x;
  const int bid = (id & 7) * 64 + (id >> 3);  // XCD-bijective (512 = 8*64)
  const int b = bid >> 5, h = (bid >> 2) & 7, q0 = (bid & 3) << 7;
  const float ratio = 1.f / (1.f + __expf(-gating[*eptr]));
  const float SC = 0.08838834764831845f;
  const size_t bh = (size_t)(b * 8 + h);

  bf16x8 qf[2][4];
  {
    const char* qa = (const char*)QA + ((bh * 512 + q0 + wv * 32 + fr) << 8) + g * 16;
#pragma unroll
    for (int mb = 0; mb < 2; ++mb)
#pragma unroll
      for (int kb = 0; kb < 4; ++kb)
        qf[mb][kb] = *(const bf16x8*)(qa + mb * 4096 + kb * 64);
  }

  auto stage = [&](int t, int buf) {
    const char* kgb = (const char*)((t < 4) ? KA : KT) + ((bh * 256 + ((size_t)(t & 3) << 6)) << 8);
    const char* vgb = (const char*)VT + (bh << 17) + (t << 7);
    char* ksd = (char*)Ks[buf] + tid * 16;
    char* vsd = (char*)Vs[buf] + tid * 16;
#pragma unroll
    for (int j = 0; j < 4; ++j) {
      const int rk = j * 16 + (tid >> 4);
      const int ck = ((tid & 15) << 4) ^ ((rk & 7) << 4);
      gload16(kgb + rk * 256 + ck, ksd + j * 4096);
      const int dv = j * 32 + (tid >> 3);
      const int cv = ((tid & 7) << 4) ^ ((dv & 7) << 4);
      gload16(vgb + dv * 1024 + cv, vsd + j * 4096);
    }
  };

  float m_run[2][4], l_run[2][4];
  f32x4 oacc[2][8];
#pragma unroll
  for (int mb = 0; mb < 2; ++mb) {
#pragma unroll
    for (int j = 0; j < 4; ++j) { m_run[mb][j] = -1e30f; l_run[mb][j] = 0.f; }
#pragma unroll
    for (int db = 0; db < 8; ++db) oacc[mb][db] = f32x4{0.f, 0.f, 0.f, 0.f};
  }

  stage(0, 0);

  for (int it = 0; it < 8; ++it) {
    const int cur = it & 1;
    if (it < 7) stage(it + 1, cur ^ 1);
    SB;
    if (it < 7) asm volatile("s_waitcnt vmcnt(8)");
    else        asm volatile("s_waitcnt vmcnt(0)");
    SB;
    BAR;
    SB;

    if (it == 4) {  // one-time Q switch: reload from QT
      const char* qt = (const char*)QT + ((bh * 512 + q0 + wv * 32 + fr) << 8) + g * 16;
#pragma unroll
      for (int mb = 0; mb < 2; ++mb)
#pragma unroll
        for (int kb = 0; kb < 4; ++kb)
          qf[mb][kb] = *(const bf16x8*)(qt + mb * 4096 + kb * 64);
    }
    const float sc = (it < 4) ? SC : SC * ratio;
    const char* kc = (const char*)Ks[cur];
    const char* vc = (const char*)Vs[cur];

    // ---- S = Q K^T : pipelined asm ds_read ----
    f32x4 s[2][4];
#pragma unroll
    for (int mb = 0; mb < 2; ++mb)
#pragma unroll
      for (int nb = 0; nb < 4; ++nb) s[mb][nb] = f32x4{0.f, 0.f, 0.f, 0.f};
    bf16x8 kfa[4], kfb[4];
#pragma unroll
    for (int kb = 0; kb < 4; ++kb) {
      const int byt = (fr * 256 + kb * 64 + g * 16) ^ ((fr & 7) << 4);
      kfa[kb] = dsread16(kc + byt);
    }
#pragma unroll
    for (int nb = 0; nb < 4; ++nb) {
      if (nb < 3) {
#pragma unroll
        for (int kb = 0; kb < 4; ++kb) {
          const int r = (nb + 1) * 16 + fr;
          const int byt = (r * 256 + kb * 64 + g * 16) ^ ((r & 7) << 4);
          if (nb & 1) kfa[kb] = dsread16(kc + byt);
          else        kfb[kb] = dsread16(kc + byt);
        }
        asm volatile("s_waitcnt lgkmcnt(4)");
      } else {
        asm volatile("s_waitcnt lgkmcnt(0)");
      }
      SB;
      __builtin_amdgcn_s_setprio(1);
#pragma unroll
      for (int kb = 0; kb < 4; ++kb) {
        bf16x8 kf = (nb & 1) ? kfb[kb] : kfa[kb];
        s[0][nb] = __builtin_amdgcn_mfma_f32_16x16x32_bf16(qf[0][kb], kf, s[0][nb], 0, 0, 0);
        s[1][nb] = __builtin_amdgcn_mfma_f32_16x16x32_bf16(qf[1][kb], kf, s[1][nb], 0, 0, 0);
      }
      __builtin_amdgcn_s_setprio(0);
    }
    SB;

    // ---- online softmax: row-max via asm ds_swizzle (16-lane groups) ----
    float red[8];
#pragma unroll
    for (int mb = 0; mb < 2; ++mb)
#pragma unroll
      for (int j = 0; j < 4; ++j) {
        float mx = -1e30f;
#pragma unroll
        for (int nb = 0; nb < 4; ++nb) {
          s[mb][nb][j] *= sc;
          mx = fmaxf(mx, s[mb][nb][j]);
        }
        red[mb * 4 + j] = mx;
      }
#define MAXR(OFF)                                                        \
    { float tmp[8];                                                      \
      _Pragma("unroll") for (int k = 0; k < 8; ++k) tmp[k] = dswz<OFF>(red[k]); \
      asm volatile("s_waitcnt lgkmcnt(0)");                              \
      SB;                                                                \
      _Pragma("unroll") for (int k = 0; k < 8; ++k) red[k] = fmaxf(red[k], tmp[k]); }
    MAXR(0x041F) MAXR(0x081F) MAXR(0x101F) MAXR(0x201F)
#undef MAXR
#pragma unroll
    for (int mb = 0; mb < 2; ++mb)
#pragma unroll
      for (int j = 0; j < 4; ++j) {
        const float mn = fmaxf(m_run[mb][j], red[mb * 4 + j]);
        const float alpha = __expf(m_run[mb][j] - mn);
        m_run[mb][j] = mn;
        l_run[mb][j] *= alpha;
#pragma unroll
        for (int db = 0; db < 8; ++db) oacc[mb][db][j] *= alpha;
      }
    // P = exp(S-m) -> bf16 -> swizzled LDS via per-lane asm ds_write_b16
#pragma unroll
    for (int mb = 0; mb < 2; ++mb)
#pragma unroll
      for (int nb = 0; nb < 4; ++nb)
#pragma unroll
        for (int j = 0; j < 4; ++j) {
          float p = __expf(s[mb][nb][j] - m_run[mb][j]);
          l_run[mb][j] += p;
          const int r = wv * 32 + mb * 16 + g * 4 + j;
          const int byt = (r * 128 + (nb * 16 + fr) * 2) ^ ((r & 7) << 4);
          dswrite2((char*)Ps + byt, (uint32_t)f2bf(p));
        }

    // ---- O += P * V ----
#pragma unroll
    for (int kb2 = 0; kb2 < 2; ++kb2) {
      bf16x8 pf[2], vf[8];
#pragma unroll
      for (int mb = 0; mb < 2; ++mb) {
        const int r = wv * 32 + mb * 16 + fr;
        const int byt = (r * 128 + kb2 * 64 + g * 16) ^ ((r & 7) << 4);
        pf[mb] = dsread16((const char*)Ps + byt);
      }
#pragma unroll
      for (int db = 0; db < 8; ++db) {
        const int rv = db * 16 + fr;
        const int byt = (rv * 128 + kb2 * 64 + g * 16) ^ ((rv & 7) << 4);
        vf[db] = dsread16(vc + byt);
      }
      asm volatile("s_waitcnt lgkmcnt(0)");
      SB;
      __builtin_amdgcn_s_setprio(1);
#pragma unroll
      for (int db = 0; db < 8; ++db) {
        oacc[0][db] = __builtin_amdgcn_mfma_f32_16x16x32_bf16(pf[0], vf[db], oacc[0][db], 0, 0, 0);
        oacc[1][db] = __builtin_amdgcn_mfma_f32_16x16x32_bf16(pf[1], vf[db], oacc[1][db], 0, 0, 0);
      }
      __builtin_amdgcn_s_setprio(0);
    }
    SB;
    BAR;
  }

#pragma unroll
  for (int mb = 0; mb < 2; ++mb)
#pragma unroll
    for (int j = 0; j < 4; ++j) {
      float lt = l_run[mb][j];
#pragma unroll
      for (int d = 1; d < 16; d <<= 1) lt += __shfl_xor(lt, d);
      float inv = 1.f / lt;
#pragma unroll
      for (int db = 0; db < 8; ++db) {
        float o = oacc[mb][db][j] * inv;
        int row = q0 + wv * 32 + mb * 16 + g * 4 + j;
        int col = h * 128 + db * 16 + fr;
        AO[(((size_t)b * 512 + row) << 10) + col] = f2bf(o);
      }
    }
}

// ---------------- LayerNorm (rows of 1024, bf16 input) ----------------
__global__ __launch_bounds__(256)
void ln_kernel(const unsigned short* __restrict__ X2, const float* __restrict__ gbase,
               const float* __restrict__ bbase, const int* __restrict__ eptr,
               unsigned short* __restrict__ XN) {
  const int row = blockIdx.x, tid = threadIdx.x;
  const unsigned short* x = X2 + ((size_t)row << 10);
  ushort4 raw = ((const ushort4*)x)[tid];
  float v0 = bf2f(raw.x), v1 = bf2f(raw.y), v2 = bf2f(raw.z), v3 = bf2f(raw.w);
  float s = v0 + v1 + v2 + v3;
  float ss = v0 * v0 + v1 * v1 + v2 * v2 + v3 * v3;
#pragma unroll
  for (int d = 1; d < 64; d <<= 1) {
    s += __shfl_xor(s, d);
    ss += __shfl_xor(ss, d);
  }
  __shared__ float red[8];
  const int wv = tid >> 6, lane = tid & 63;
  if (lane == 0) { red[wv] = s; red[4 + wv] = ss; }
  __syncthreads();
  s = red[0] + red[1] + red[2] + red[3];
  ss = red[4] + red[5] + red[6] + red[7];
  const float mu = s * 0.0009765625f;
  const float var = ss * 0.0009765625f - mu * mu;
  const float inv = rsqrtf(var + 1e-5f);
  const int e = *eptr;
  const float* gg = gbase + e * 1024 + tid * 4;
  const float* bb = bbase + e * 1024 + tid * 4;
  ushort4 o;
  o.x = f2bf((v0 - mu) * inv * gg[0] + bb[0]);
  o.y = f2bf((v1 - mu) * inv * gg[1] + bb[1]);
  o.z = f2bf((v2 - mu) * inv * gg[2] + bb[2]);
  o.w = f2bf((v3 - mu) * inv * gg[3] + bb[3]);
  *(ushort4*)&XN[((size_t)row << 10) + tid * 4] = o;
}

// ---------------- host launcher ----------------
extern "C" void kernel_launch(void* const* d_in, const int* in_sizes, int n_in,
                              void* d_out, int out_size, void* d_ws, size_t ws_size,
                              hipStream_t stream) {
  (void)in_sizes; (void)n_in; (void)out_size; (void)ws_size;
  const float* x      = (const float*)d_in[0];
  const float* h_a    = (const float*)d_in[1];
  const float* h_t    = (const float*)d_in[2];
  const float* W_qa   = (const float*)d_in[3];
  const float* b_qa   = (const float*)d_in[4];
  const float* W_ka   = (const float*)d_in[5];
  const float* b_ka   = (const float*)d_in[6];
  const float* W_va   = (const float*)d_in[7];
  const float* b_va   = (const float*)d_in[8];
  const float* W_qt   = (const float*)d_in[9];
  const float* b_qt   = (const float*)d_in[10];
  const float* W_kt   = (const float*)d_in[11];
  const float* b_kt   = (const float*)d_in[12];
  const float* W_vt   = (const float*)d_in[13];
  const float* b_vt   = (const float*)d_in[14];
  const float* W_o    = (const float*)d_in[15];
  const float* b_o    = (const float*)d_in[16];
  const float* W_ffn  = (const float*)d_in[17];
  const float* b_ffn  = (const float*)d_in[18];
  const float* gamma  = (const float*)d_in[19];
  const float* beta   = (const float*)d_in[20];
  const float* gating = (const float*)d_in[21];
  const int*   eptr   = (const int*)d_in[22];

  char* ws = (char*)d_ws;
  unsigned short* XB  = (unsigned short*)(ws + 0);          // 16 MB
  unsigned short* HAB = (unsigned short*)(ws + 16777216);   // 8 MB
  unsigned short* HTB = (unsigned short*)(ws + 25165824);   // 8 MB
  unsigned short* X2b = (unsigned short*)(ws + 0);          // 16 MB overlay (bf16)
  unsigned short* WW  = (unsigned short*)(ws + 33554432);   // 8 x 2 MB
  unsigned short* QAb = (unsigned short*)(ws + 50331648);   // 16 MB
  unsigned short* XN  = QAb;                                // overlay
  unsigned short* QTb = (unsigned short*)(ws + 67108864);   // 16 MB
  unsigned short* KAb = (unsigned short*)(ws + 83886080);   // 8 MB
  unsigned short* KTb = (unsigned short*)(ws + 92274688);   // 8 MB
  unsigned short* VTb = (unsigned short*)(ws + 100663296);  // 16 MB (b,h,d,512)
  unsigned short* AOb = (unsigned short*)(ws + 117440512);  // 16 MB
  float* COS = (float*)(ws + 134217728);
  float* SIN = (float*)(ws + 134479872);

  prep_all<<<12544, 256, 0, stream>>>(x, h_a, h_t,
      W_qa, W_ka, W_va, W_qt, W_kt, W_vt, W_o, W_ffn, eptr,
      XB, HAB, HTB, WW, COS, SIN);

  // Fused Q + K|V projections: 1024 blocks (r13 loop, r10 plumbing)
  gemm3r<0><<<dim3(1024), 512, 0, stream>>>(XB, HAB, HTB,
      WW + 0ull * 1048576, WW + 3ull * 1048576,   // W_qa, W_qt
      WW + 1ull * 1048576, WW + 2ull * 1048576,   // W_ka, W_va
      WW + 4ull * 1048576, WW + 5ull * 1048576,   // W_kt, W_vt
      b_qa, b_qt, b_ka, b_va, b_kt, b_vt,
      eptr, COS, SIN,
      QAb, QTb, KAb, KTb, VTb, nullptr, nullptr, nullptr);

  attn_kernel<<<512, 256, 0, stream>>>(QAb, QTb, KAb, KTb, VTb, AOb, gating, eptr);

  // O-proj + residual -> bf16 X2
  gemm3r<2><<<dim3(256), 512, 0, stream>>>(AOb, nullptr, nullptr,
      WW + 6ull * 1048576, nullptr, nullptr, nullptr, nullptr, nullptr,
      b_o, nullptr, nullptr, nullptr, nullptr, nullptr,
      eptr, nullptr, nullptr,
      nullptr, nullptr, nullptr, nullptr, nullptr, x, X2b, nullptr);

  ln_kernel<<<8192, 256, 0, stream>>>(X2b, gamma, beta, eptr, XN);

  gemm3r<3><<<dim3(256), 512, 0, stream>>>(XN, nullptr, nullptr,
      WW + 7ull * 1048576, nullptr, nullptr, nullptr, nullptr, nullptr,
      b_ffn, nullptr, nullptr, nullptr, nullptr, nullptr,
      eptr, nullptr, nullptr,
      nullptr, nullptr, nullptr, nullptr, nullptr, nullptr, nullptr, (float*)d_out);
}

// Round 15
// 214.906 us; speedup vs baseline: 1.1495x; 1.1495x over previous
//
#include <hip/hip_runtime.h>
#include <stdint.h>

typedef __bf16 bf16x8 __attribute__((ext_vector_type(8)));
typedef float f32x4 __attribute__((ext_vector_type(4)));
typedef unsigned short u16x8 __attribute__((ext_vector_type(8)));

typedef const __attribute__((address_space(1))) void* gas_ptr;
typedef __attribute__((address_space(3))) void* las_ptr;
typedef const __attribute__((address_space(3))) char* lds_c3;

__device__ __forceinline__ void gload16(const void* g, void* l) {
  __builtin_amdgcn_global_load_lds((gas_ptr)g, (las_ptr)l, 16, 0, 0);
}

__device__ __forceinline__ bf16x8 dsread16(const char* p) {
  bf16x8 r;
  asm volatile("ds_read_b128 %0, %1" : "=v"(r) : "v"((lds_c3)p));
  return r;
}
__device__ __forceinline__ void dswrite2(char* p, uint32_t v) {
  asm volatile("ds_write_b16 %0, %1" : : "v"((las_ptr)p), "v"(v));
}
template <int OFF>
__device__ __forceinline__ float dswz(float x) {
  float r;
  asm volatile("ds_swizzle_b32 %0, %1 offset:%c2" : "=v"(r) : "v"(x), "i"(OFF));
  return r;
}

__device__ __forceinline__ unsigned short f2bf(float f) {
  uint32_t u = __float_as_uint(f);
  u += 0x7FFFu + ((u >> 16) & 1u);
  return (unsigned short)(u >> 16);
}
__device__ __forceinline__ float bf2f(unsigned short u) {
  return __uint_as_float(((uint32_t)u) << 16);
}

#define SB __builtin_amdgcn_sched_barrier(0)
#define BAR __builtin_amdgcn_s_barrier()
#define LGK0 asm volatile("s_waitcnt lgkmcnt(0)")

// ---------------- fused prep: all f32->bf16 converts + RoPE table ----------
__device__ __forceinline__ void conv8(const float* __restrict__ src,
                                      unsigned short* __restrict__ dst, int i) {
  const float4* s4 = (const float4*)src;
  float4 a = s4[2 * i], b = s4[2 * i + 1];
  u16x8 r;
  r[0] = f2bf(a.x); r[1] = f2bf(a.y); r[2] = f2bf(a.z); r[3] = f2bf(a.w);
  r[4] = f2bf(b.x); r[5] = f2bf(b.y); r[6] = f2bf(b.z); r[7] = f2bf(b.w);
  *(u16x8*)&dst[(size_t)i * 8] = r;
}

__global__ __launch_bounds__(256)
void prep_all(const float* __restrict__ x, const float* __restrict__ h_a,
              const float* __restrict__ h_t,
              const float* W0, const float* W1, const float* W2, const float* W3,
              const float* W4, const float* W5, const float* W6, const float* W7,
              const int* __restrict__ eptr,
              unsigned short* __restrict__ XB, unsigned short* __restrict__ HAB,
              unsigned short* __restrict__ HTB, unsigned short* __restrict__ WW,
              float* __restrict__ cosb, float* __restrict__ sinb) {
  const int blk = blockIdx.x, tid = threadIdx.x;
  if (blk < 4096) {
    conv8(x, XB, blk * 256 + tid);
  } else if (blk < 6144) {
    conv8(h_a, HAB, (blk - 4096) * 256 + tid);
  } else if (blk < 8192) {
    conv8(h_t, HTB, (blk - 6144) * 256 + tid);
  } else if (blk < 12288) {
    const int w = (blk - 8192) >> 9;
    const int i = ((blk - 8192) & 511) * 256 + tid;
    const float* wp;
    switch (w) {
      case 0: wp = W0; break; case 1: wp = W1; break;
      case 2: wp = W2; break; case 3: wp = W3; break;
      case 4: wp = W4; break; case 5: wp = W5; break;
      case 6: wp = W6; break; default: wp = W7; break;
    }
    conv8(wp + (size_t)(*eptr) * 1048576, WW + (size_t)w * 1048576, i);
  } else {
    const int i = (blk - 12288) * 256 + tid;  // 0..65535
    const int t = i >> 7, d = i & 127;
    const int f = d & 63;
    float invf = expf(-0.14391156831212787f * (float)f);  // 10000^(-f/64)
    float ang = (float)t * invf;
    float s, c;
    sincosf(ang, &s, &c);
    cosb[i] = c;
    sinb[i] = s;
  }
}

// ======== 3-ring counted-vmcnt GEMM: BM=256, BN=128, BK=64, 8 waves =========
// (round-13 best-measured structure; MODE 2 stores bf16 X2)
template <int MODE>
__global__ __launch_bounds__(512, 1)
void gemm3r(const unsigned short* __restrict__ A0, const unsigned short* __restrict__ A1,
            const unsigned short* __restrict__ W0, const unsigned short* __restrict__ W1,
            const unsigned short* __restrict__ W2, const unsigned short* __restrict__ W3,
            const float* __restrict__ bias0, const float* __restrict__ bias1,
            const float* __restrict__ bias2, const float* __restrict__ bias3,
            const int* __restrict__ eptr, const float* __restrict__ ctab,
            const float* __restrict__ stab,
            unsigned short* __restrict__ out0, unsigned short* __restrict__ out1,
            unsigned short* __restrict__ outV,
            const float* __restrict__ resid, unsigned short* __restrict__ outbf,
            float* __restrict__ outf) {
  __shared__ __align__(16) char AL[98304];
  __shared__ __align__(16) char BL[49152];
  const int tid = threadIdx.x;
  const int lane = tid & 63, wid = tid >> 6, fr = lane & 15, g = lane >> 4;
  const int wm = wid >> 1, wn = wid & 1;  // 4M x 2N
  const int id = blockIdx.x;
  constexpr int CPX = (MODE == 0) ? 64 : 32;  // grid.x / 8
  const int swz = (id & 7) * CPX + (id >> 3);
  constexpr int NBNS = (MODE <= 1) ? 4 : 3;   // log2(bn count)
  const int bm = swz >> NBNS;
  const int bn = swz & ((1 << NBNS) - 1);
  const int z = (MODE == 1) ? blockIdx.y : 0;
  const int e = *eptr;

  const unsigned short* Asel;
  const unsigned short* Wsel;
  const float* bias;
  int half = 0, cb0;
  if constexpr (MODE == 0) {
    Asel = A0;
    half = bn >> 3;
    Wsel = half ? W1 : W0;
    bias = (half ? bias1 : bias0) + e * 1024;
    cb0 = (bn & 7) * 128;
  } else if constexpr (MODE == 1) {
    Asel = z ? A1 : A0;
    half = bn >> 3;
    Wsel = z ? (half ? W3 : W2) : (half ? W1 : W0);
    bias = (z ? (half ? bias3 : bias2) : (half ? bias1 : bias0)) + e * 1024;
    cb0 = (bn & 7) * 128;
  } else {
    Asel = A0;
    Wsel = W0;
    bias = bias0 + e * 1024;
    cb0 = bn * 128;
  }

  const char* Ab = (const char*)Asel + (size_t)bm * 256 * 2048;
  const char* Bb = (const char*)Wsel + (size_t)cb0 * 2048;

  const int csw = (((tid & 7) ^ ((tid >> 3) & 7)) << 4);
  const char* Ags = Ab + (tid >> 3) * 2048 + csw;
  const char* Bgs = Bb + (tid >> 3) * 2048 + csw;
  char* Ald = AL + tid * 16;
  char* Bld = BL + tid * 16;

#define STA(T, BUF)                                                         \
  { const char* s_ = Ags + (T) * 128;                                       \
    char* d_ = Ald + (BUF) * 32768;                                         \
    gload16(s_, d_);                  gload16(s_ + 131072, d_ + 8192);      \
    gload16(s_ + 262144, d_ + 16384); gload16(s_ + 393216, d_ + 24576); }
#define STB(T, BUF)                                                         \
  { const char* s_ = Bgs + (T) * 128;                                       \
    char* d_ = Bld + (BUF) * 16384;                                         \
    gload16(s_, d_);                  gload16(s_ + 131072, d_ + 8192); }

  const int lsw7 = fr & 7;
  const int ksel = (wid & 4) ? 4 : 0;
  const int cA = ((ksel + g) ^ lsw7) << 4;
  const int cB = (((4 - ksel) + g) ^ lsw7) << 4;
  const int arow = (wm * 64 + fr) * 128;
  const int brow = (wn * 64 + fr) * 128;

  f32x4 acc[4][4];
#pragma unroll
  for (int m = 0; m < 4; ++m)
#pragma unroll
    for (int n = 0; n < 4; ++n) acc[m][n] = f32x4{0.f, 0.f, 0.f, 0.f};
  bf16x8 af[4], bf[4];

#define RDAB(BASEA, BASEB, C)                                               \
  { const char* pa_ = (BASEA) + arow + (C);                                 \
    const char* pb_ = (BASEB) + brow + (C);                                 \
    _Pragma("unroll") for (int m = 0; m < 4; ++m)                           \
        af[m] = dsread16(pa_ + m * 2048);                                   \
    _Pragma("unroll") for (int n = 0; n < 4; ++n)                           \
        bf[n] = dsread16(pb_ + n * 2048); }

#define MF16                                                                \
  __builtin_amdgcn_s_setprio(1);                                            \
  _Pragma("unroll") for (int m = 0; m < 4; ++m)                             \
    _Pragma("unroll") for (int n = 0; n < 4; ++n)                           \
        acc[m][n] = __builtin_amdgcn_mfma_f32_16x16x32_bf16(                \
            af[m], bf[n], acc[m][n], 0, 0, 0);                              \
  __builtin_amdgcn_s_setprio(0);

  STA(0, 0); STB(0, 0); STA(1, 1); STB(1, 1);

  int bc = 0;
#pragma unroll 1
  for (int t = 0; t < 16; ++t) {
    SB;
    if (t <= 14) asm volatile("s_waitcnt vmcnt(6)");
    else         asm volatile("s_waitcnt vmcnt(0)");
    BAR; SB;
    const char* ALc = AL + bc * 32768;
    const char* BLc = BL + bc * 16384;
    const int bs = bc ? bc - 1 : 2;  // (t+2)%3
    RDAB(ALc, BLc, cA); SB;
    if (t <= 13) STA(t + 2, bs);
    SB; LGK0; SB;
    MF16 SB;
    RDAB(ALc, BLc, cB); SB;
    if (t <= 13) STB(t + 2, bs);
    SB; LGK0; SB;
    MF16 SB;
    bc = (bc == 2) ? 0 : bc + 1;
  }
#undef RDAB
#undef MF16
#undef STA
#undef STB

  // ---------------- epilogue ----------------
  const int wrow0 = bm * 256 + wm * 64;
#pragma unroll
  for (int m = 0; m < 4; ++m) {
#pragma unroll
    for (int n = 0; n < 4; ++n) {
      const int lc = wn * 64 + n * 16 + fr;
      const int gc = cb0 + lc;
      const float bv = bias[gc];
#pragma unroll
      for (int j = 0; j < 4; ++j) {
        const int grow = wrow0 + m * 16 + g * 4 + j;
        float v = acc[m][n][j] + bv;
        if constexpr (MODE == 0) {
          const int t = grow & 511, bb = grow >> 9;
          const int hh = gc >> 7, dd = gc & 127;
          float pv = __shfl_xor(v, 1);
          float cs = ctab[t * 128 + dd], sn = stab[t * 128 + dd];
          float rh = (dd & 1) ? pv : -pv;
          float o = v * cs + rh * sn;
          unsigned short* dst = half ? out1 : out0;
          dst[(((size_t)(bb * 8 + hh) * 512 + t) << 7) + dd] = f2bf(o);
        } else if constexpr (MODE == 1) {
          const int t = grow & 255, bb = grow >> 8;
          const int hh = gc >> 7, dd = gc & 127;
          if (half == 0) {  // K: RoPE, LSEQ=256
            float pv = __shfl_xor(v, 1);
            float cs = ctab[t * 128 + dd], sn = stab[t * 128 + dd];
            float rh = (dd & 1) ? pv : -pv;
            float o = v * cs + rh * sn;
            unsigned short* dst = z ? out1 : out0;
            dst[(((size_t)(bb * 8 + hh) * 256 + t) << 7) + dd] = f2bf(o);
          } else {  // V: transposed (b,h,d,512)
            outV[(((size_t)(bb * 8 + hh) << 7) + dd) * 512 + z * 256 + t] = f2bf(v);
          }
        } else if constexpr (MODE == 2) {
          const size_t idx = ((size_t)grow << 10) + gc;
          outbf[idx] = f2bf(v + resid[idx]);  // X2 in bf16 (traffic halved)
        } else {
          const size_t idx = ((size_t)grow << 10) + gc;
          outf[idx] = fmaxf(v, 0.f);
        }
      }
    }
  }
}

// ---------------- fused dual-stream flash attention (r13: dbuf + XCD swz) --
__global__ __launch_bounds__(256, 2)
void attn_kernel(const unsigned short* __restrict__ QA, const unsigned short* __restrict__ QT,
                 const unsigned short* __restrict__ KA, const unsigned short* __restrict__ KT,
                 const unsigned short* __restrict__ VT,  // (b,h,d=128,n=512)
                 unsigned short* __restrict__ AO,        // (b,t,1024)
                 const float* __restrict__ gating, const int* __restrict__ eptr) {
  __shared__ unsigned short Ks[2][8192];
  __shared__ unsigned short Vs[2][8192];
  __shared__ unsigned short Ps[8192];
  const int tid = threadIdx.x, lane = tid & 63, wv = tid >> 6;
  const int fr = lane & 15, g = lane >> 4;
  const int id = blockIdx.x;
  const int bid = (id & 7) * 64 + (id >> 3);  // XCD-bijective (512 = 8*64)
  const int b = bid >> 5, h = (bid >> 2) & 7, q0 = (bid & 3) << 7;
  const float ratio = 1.f / (1.f + __expf(-gating[*eptr]));
  const float SC = 0.08838834764831845f;
  const size_t bh = (size_t)(b * 8 + h);

  bf16x8 qf[2][4];
  {
    const char* qa = (const char*)QA + ((bh * 512 + q0 + wv * 32 + fr) << 8) + g * 16;
#pragma unroll
    for (int mb = 0; mb < 2; ++mb)
#pragma unroll
      for (int kb = 0; kb < 4; ++kb)
        qf[mb][kb] = *(const bf16x8*)(qa + mb * 4096 + kb * 64);
  }

  auto stage = [&](int t, int buf) {
    const char* kgb = (const char*)((t < 4) ? KA : KT) + ((bh * 256 + ((size_t)(t & 3) << 6)) << 8);
    const char* vgb = (const char*)VT + (bh << 17) + (t << 7);
    char* ksd = (char*)Ks[buf] + tid * 16;
    char* vsd = (char*)Vs[buf] + tid * 16;
#pragma unroll
    for (int j = 0; j < 4; ++j) {
      const int rk = j * 16 + (tid >> 4);
      const int ck = ((tid & 15) << 4) ^ ((rk & 7) << 4);
      gload16(kgb + rk * 256 + ck, ksd + j * 4096);
      const int dv = j * 32 + (tid >> 3);
      const int cv = ((tid & 7) << 4) ^ ((dv & 7) << 4);
      gload16(vgb + dv * 1024 + cv, vsd + j * 4096);
    }
  };

  float m_run[2][4], l_run[2][4];
  f32x4 oacc[2][8];
#pragma unroll
  for (int mb = 0; mb < 2; ++mb) {
#pragma unroll
    for (int j = 0; j < 4; ++j) { m_run[mb][j] = -1e30f; l_run[mb][j] = 0.f; }
#pragma unroll
    for (int db = 0; db < 8; ++db) oacc[mb][db] = f32x4{0.f, 0.f, 0.f, 0.f};
  }

  stage(0, 0);

  for (int it = 0; it < 8; ++it) {
    const int cur = it & 1;
    if (it < 7) stage(it + 1, cur ^ 1);
    SB;
    if (it < 7) asm volatile("s_waitcnt vmcnt(8)");
    else        asm volatile("s_waitcnt vmcnt(0)");
    SB;
    BAR;
    SB;

    if (it == 4) {  // one-time Q switch: reload from QT
      const char* qt = (const char*)QT + ((bh * 512 + q0 + wv * 32 + fr) << 8) + g * 16;
#pragma unroll
      for (int mb = 0; mb < 2; ++mb)
#pragma unroll
        for (int kb = 0; kb < 4; ++kb)
          qf[mb][kb] = *(const bf16x8*)(qt + mb * 4096 + kb * 64);
    }
    const float sc = (it < 4) ? SC : SC * ratio;
    const char* kc = (const char*)Ks[cur];
    const char* vc = (const char*)Vs[cur];

    // ---- S = Q K^T : pipelined asm ds_read ----
    f32x4 s[2][4];
#pragma unroll
    for (int mb = 0; mb < 2; ++mb)
#pragma unroll
      for (int nb = 0; nb < 4; ++nb) s[mb][nb] = f32x4{0.f, 0.f, 0.f, 0.f};
    bf16x8 kfa[4], kfb[4];
#pragma unroll
    for (int kb = 0; kb < 4; ++kb) {
      const int byt = (fr * 256 + kb * 64 + g * 16) ^ ((fr & 7) << 4);
      kfa[kb] = dsread16(kc + byt);
    }
#pragma unroll
    for (int nb = 0; nb < 4; ++nb) {
      if (nb < 3) {
#pragma unroll
        for (int kb = 0; kb < 4; ++kb) {
          const int r = (nb + 1) * 16 + fr;
          const int byt = (r * 256 + kb * 64 + g * 16) ^ ((r & 7) << 4);
          if (nb & 1) kfa[kb] = dsread16(kc + byt);
          else        kfb[kb] = dsread16(kc + byt);
        }
        asm volatile("s_waitcnt lgkmcnt(4)");
      } else {
        asm volatile("s_waitcnt lgkmcnt(0)");
      }
      SB;
      __builtin_amdgcn_s_setprio(1);
#pragma unroll
      for (int kb = 0; kb < 4; ++kb) {
        bf16x8 kf = (nb & 1) ? kfb[kb] : kfa[kb];
        s[0][nb] = __builtin_amdgcn_mfma_f32_16x16x32_bf16(qf[0][kb], kf, s[0][nb], 0, 0, 0);
        s[1][nb] = __builtin_amdgcn_mfma_f32_16x16x32_bf16(qf[1][kb], kf, s[1][nb], 0, 0, 0);
      }
      __builtin_amdgcn_s_setprio(0);
    }
    SB;

    // ---- online softmax: row-max via asm ds_swizzle (16-lane groups) ----
    float red[8];
#pragma unroll
    for (int mb = 0; mb < 2; ++mb)
#pragma unroll
      for (int j = 0; j < 4; ++j) {
        float mx = -1e30f;
#pragma unroll
        for (int nb = 0; nb < 4; ++nb) {
          s[mb][nb][j] *= sc;
          mx = fmaxf(mx, s[mb][nb][j]);
        }
        red[mb * 4 + j] = mx;
      }
#define MAXR(OFF)                                                        \
    { float tmp[8];                                                      \
      _Pragma("unroll") for (int k = 0; k < 8; ++k) tmp[k] = dswz<OFF>(red[k]); \
      asm volatile("s_waitcnt lgkmcnt(0)");                              \
      SB;                                                                \
      _Pragma("unroll") for (int k = 0; k < 8; ++k) red[k] = fmaxf(red[k], tmp[k]); }
    MAXR(0x041F) MAXR(0x081F) MAXR(0x101F) MAXR(0x201F)
#undef MAXR
#pragma unroll
    for (int mb = 0; mb < 2; ++mb)
#pragma unroll
      for (int j = 0; j < 4; ++j) {
        const float mn = fmaxf(m_run[mb][j], red[mb * 4 + j]);
        const float alpha = __expf(m_run[mb][j] - mn);
        m_run[mb][j] = mn;
        l_run[mb][j] *= alpha;
#pragma unroll
        for (int db = 0; db < 8; ++db) oacc[mb][db][j] *= alpha;
      }
    // P = exp(S-m) -> bf16 -> swizzled LDS via per-lane asm ds_write_b16
#pragma unroll
    for (int mb = 0; mb < 2; ++mb)
#pragma unroll
      for (int nb = 0; nb < 4; ++nb)
#pragma unroll
        for (int j = 0; j < 4; ++j) {
          float p = __expf(s[mb][nb][j] - m_run[mb][j]);
          l_run[mb][j] += p;
          const int r = wv * 32 + mb * 16 + g * 4 + j;
          const int byt = (r * 128 + (nb * 16 + fr) * 2) ^ ((r & 7) << 4);
          dswrite2((char*)Ps + byt, (uint32_t)f2bf(p));
        }

    // ---- O += P * V ----
#pragma unroll
    for (int kb2 = 0; kb2 < 2; ++kb2) {
      bf16x8 pf[2], vf[8];
#pragma unroll
      for (int mb = 0; mb < 2; ++mb) {
        const int r = wv * 32 + mb * 16 + fr;
        const int byt = (r * 128 + kb2 * 64 + g * 16) ^ ((r & 7) << 4);
        pf[mb] = dsread16((const char*)Ps + byt);
      }
#pragma unroll
      for (int db = 0; db < 8; ++db) {
        const int rv = db * 16 + fr;
        const int byt = (rv * 128 + kb2 * 64 + g * 16) ^ ((rv & 7) << 4);
        vf[db] = dsread16(vc + byt);
      }
      asm volatile("s_waitcnt lgkmcnt(0)");
      SB;
      __builtin_amdgcn_s_setprio(1);
#pragma unroll
      for (int db = 0; db < 8; ++db) {
        oacc[0][db] = __builtin_amdgcn_mfma_f32_16x16x32_bf16(pf[0], vf[db], oacc[0][db], 0, 0, 0);
        oacc[1][db] = __builtin_amdgcn_mfma_f32_16x16x32_bf16(pf[1], vf[db], oacc[1][db], 0, 0, 0);
      }
      __builtin_amdgcn_s_setprio(0);
    }
    SB;
    BAR;
  }

#pragma unroll
  for (int mb = 0; mb < 2; ++mb)
#pragma unroll
    for (int j = 0; j < 4; ++j) {
      float lt = l_run[mb][j];
#pragma unroll
      for (int d = 1; d < 16; d <<= 1) lt += __shfl_xor(lt, d);
      float inv = 1.f / lt;
#pragma unroll
      for (int db = 0; db < 8; ++db) {
        float o = oacc[mb][db][j] * inv;
        int row = q0 + wv * 32 + mb * 16 + g * 4 + j;
        int col = h * 128 + db * 16 + fr;
        AO[(((size_t)b * 512 + row) << 10) + col] = f2bf(o);
      }
    }
}

// ---------------- LayerNorm (rows of 1024, bf16 input) ----------------
__global__ __launch_bounds__(256)
void ln_kernel(const unsigned short* __restrict__ X2, const float* __restrict__ gbase,
               const float* __restrict__ bbase, const int* __restrict__ eptr,
               unsigned short* __restrict__ XN) {
  const int row = blockIdx.x, tid = threadIdx.x;
  const unsigned short* x = X2 + ((size_t)row << 10);
  ushort4 raw = ((const ushort4*)x)[tid];
  float v0 = bf2f(raw.x), v1 = bf2f(raw.y), v2 = bf2f(raw.z), v3 = bf2f(raw.w);
  float s = v0 + v1 + v2 + v3;
  float ss = v0 * v0 + v1 * v1 + v2 * v2 + v3 * v3;
#pragma unroll
  for (int d = 1; d < 64; d <<= 1) {
    s += __shfl_xor(s, d);
    ss += __shfl_xor(ss, d);
  }
  __shared__ float red[8];
  const int wv = tid >> 6, lane = tid & 63;
  if (lane == 0) { red[wv] = s; red[4 + wv] = ss; }
  __syncthreads();
  s = red[0] + red[1] + red[2] + red[3];
  ss = red[4] + red[5] + red[6] + red[7];
  const float mu = s * 0.0009765625f;
  const float var = ss * 0.0009765625f - mu * mu;
  const float inv = rsqrtf(var + 1e-5f);
  const int e = *eptr;
  const float* gg = gbase + e * 1024 + tid * 4;
  const float* bb = bbase + e * 1024 + tid * 4;
  ushort4 o;
  o.x = f2bf((v0 - mu) * inv * gg[0] + bb[0]);
  o.y = f2bf((v1 - mu) * inv * gg[1] + bb[1]);
  o.z = f2bf((v2 - mu) * inv * gg[2] + bb[2]);
  o.w = f2bf((v3 - mu) * inv * gg[3] + bb[3]);
  *(ushort4*)&XN[((size_t)row << 10) + tid * 4] = o;
}

// ---------------- host launcher ----------------
extern "C" void kernel_launch(void* const* d_in, const int* in_sizes, int n_in,
                              void* d_out, int out_size, void* d_ws, size_t ws_size,
                              hipStream_t stream) {
  (void)in_sizes; (void)n_in; (void)out_size; (void)ws_size;
  const float* x      = (const float*)d_in[0];
  const float* h_a    = (const float*)d_in[1];
  const float* h_t    = (const float*)d_in[2];
  const float* W_qa   = (const float*)d_in[3];
  const float* b_qa   = (const float*)d_in[4];
  const float* W_ka   = (const float*)d_in[5];
  const float* b_ka   = (const float*)d_in[6];
  const float* W_va   = (const float*)d_in[7];
  const float* b_va   = (const float*)d_in[8];
  const float* W_qt   = (const float*)d_in[9];
  const float* b_qt   = (const float*)d_in[10];
  const float* W_kt   = (const float*)d_in[11];
  const float* b_kt   = (const float*)d_in[12];
  const float* W_vt   = (const float*)d_in[13];
  const float* b_vt   = (const float*)d_in[14];
  const float* W_o    = (const float*)d_in[15];
  const float* b_o    = (const float*)d_in[16];
  const float* W_ffn  = (const float*)d_in[17];
  const float* b_ffn  = (const float*)d_in[18];
  const float* gamma  = (const float*)d_in[19];
  const float* beta   = (const float*)d_in[20];
  const float* gating = (const float*)d_in[21];
  const int*   eptr   = (const int*)d_in[22];

  char* ws = (char*)d_ws;
  unsigned short* XB  = (unsigned short*)(ws + 0);          // 16 MB
  unsigned short* HAB = (unsigned short*)(ws + 16777216);   // 8 MB
  unsigned short* HTB = (unsigned short*)(ws + 25165824);   // 8 MB
  unsigned short* X2b = (unsigned short*)(ws + 0);          // 16 MB overlay (bf16)
  unsigned short* WW  = (unsigned short*)(ws + 33554432);   // 8 x 2 MB
  unsigned short* QAb = (unsigned short*)(ws + 50331648);   // 16 MB
  unsigned short* XN  = QAb;                                // overlay
  unsigned short* QTb = (unsigned short*)(ws + 67108864);   // 16 MB
  unsigned short* KAb = (unsigned short*)(ws + 83886080);   // 8 MB
  unsigned short* KTb = (unsigned short*)(ws + 92274688);   // 8 MB
  unsigned short* VTb = (unsigned short*)(ws + 100663296);  // 16 MB (b,h,d,512)
  unsigned short* AOb = (unsigned short*)(ws + 117440512);  // 16 MB
  float* COS = (float*)(ws + 134217728);
  float* SIN = (float*)(ws + 134479872);

  prep_all<<<12544, 256, 0, stream>>>(x, h_a, h_t,
      W_qa, W_ka, W_va, W_qt, W_kt, W_vt, W_o, W_ffn, eptr,
      XB, HAB, HTB, WW, COS, SIN);

  // Q projections (qa|qt fused, N=2048): 32 bm x 16 bn = 512 blocks
  gemm3r<0><<<dim3(512), 512, 0, stream>>>(XB, nullptr,
      WW + 0ull * 1048576, WW + 3ull * 1048576, nullptr, nullptr,
      b_qa, b_qt, nullptr, nullptr, eptr, COS, SIN,
      QAb, QTb, nullptr, nullptr, nullptr, nullptr);

  // K|V projections: 16 bm x 16 bn, 2 streams
  gemm3r<1><<<dim3(256, 2), 512, 0, stream>>>(HAB, HTB,
      WW + 1ull * 1048576, WW + 2ull * 1048576,
      WW + 4ull * 1048576, WW + 5ull * 1048576,
      b_ka, b_va, b_kt, b_vt, eptr, COS, SIN,
      KAb, KTb, VTb, nullptr, nullptr, nullptr);

  attn_kernel<<<512, 256, 0, stream>>>(QAb, QTb, KAb, KTb, VTb, AOb, gating, eptr);

  // O-proj + residual -> bf16 X2
  gemm3r<2><<<dim3(256), 512, 0, stream>>>(AOb, nullptr,
      WW + 6ull * 1048576, nullptr, nullptr, nullptr,
      b_o, nullptr, nullptr, nullptr, eptr, nullptr, nullptr,
      nullptr, nullptr, nullptr, x, X2b, nullptr);

  ln_kernel<<<8192, 256, 0, stream>>>(X2b, gamma, beta, eptr, XN);

  gemm3r<3><<<dim3(256), 512, 0, stream>>>(XN, nullptr,
      WW + 7ull * 1048576, nullptr, nullptr, nullptr,
      b_ffn, nullptr, nullptr, nullptr, eptr, nullptr, nullptr,
      nullptr, nullptr, nullptr, nullptr, nullptr, (float*)d_out);
}